// Round 5
// baseline (868.959 us; speedup 1.0000x reference)
//
#include <hip/hip_runtime.h>
#include <math.h>

// ForwardSumLoss (CTC forward), MI355X — fused single kernel + tiny mean.
// One block per batch. Wave 0: 801-state recursion in registers (16/lane),
// cross-lane hop = single DPP wave_shr:1 (pure VALU). NEW in R5: chunk
// kC=8 with a CHUNK-WIDE WEIGHT PRELOAD — all 8 steps' weights loaded at
// chunk start into 16 NAMED float4 locals (compile-time indexed, 64 VGPR)
// via a straight run of 16 ds_read_b128, then 8 steps of pure VALU. LDS
// latency paid once per 8 steps, not once per step.
// [R4 lesson: removing ds_bpermute was ~neutral (344->339us) -> the stall
//  is per-step exposed ds_read latency (~250-300cy under producer
//  contention, magnitude calibrated by R2's +300cy/step when one extra
//  LDS round-trip entered the step chain).]
// [R1 lesson: persistent wA/wB double-buffer regressed — but that was
//  depth-1 per-step buffering with long live ranges; this is a flat
//  batch of fresh locals per chunk.]
// Waves 1-3: producers (load+exp+stage, 800 float4/chunk, STATIC rg[5]
// prefetch buffers). Wave 1 reduces per-row softmax denominators.

namespace {
constexpr int kB = 64;
constexpr int kT = 2000;
constexpr int kL = 400;
constexpr int kC = 8;             // timesteps per chunk
constexpr int kRow = 408;         // floats per staged row (400 + 8 guard)
constexpr float kEblank = 0.36787944117144233f;   // exp(-1)
}

__global__ __launch_bounds__(256, 1) void ctc_forward_kernel(
        const float* __restrict__ attn, const int* __restrict__ text_lens,
        const int* __restrict__ mel_lens, float* __restrict__ loss_ws) {
    __shared__ __align__(16) float wbuf[2][kC][kRow];   // 26112 B
    __shared__ float psum[2][kC * 100];                 // 6400 B
    __shared__ double sLd;

    const int b    = blockIdx.x;
    const int tid  = threadIdx.x;
    const int lane = tid & 63;
    const int wv   = tid >> 6;
    const int Lb = text_lens[b];
    const int Tb = mel_lens[b];
    const int Sb = 2 * Lb + 1;
    const int nck = (Tb + kC - 1) / kC;

    const float4* __restrict__ rp4 = (const float4*)(attn + (size_t)b * kT * kL);

    // guard zeros: words [400,408) of every row, both slots (128 writes)
    if (tid < 128) {
        const int slot = tid >> 6, row = (tid >> 3) & 7, j = tid & 7;
        wbuf[slot][row][400 + j] = 0.f;
    }

    // ---------------- producers (waves 1-3) ----------------
    const int pid = tid - 64;          // 0..191
    float4 rgE[5], rgO[5];             // STATIC buffers — never runtime-indexed

    auto load_chunk = [&](int ck, float4 (&rg)[5]) {
        const int t0 = ck * kC;
        #pragma unroll
        for (int i = 0; i < 5; ++i) {
            const int task = pid + 192 * i;
            if (task < kC * 100) {
                const int r = task / 100, q = task - r * 100;
                if (t0 + r < Tb) rg[i] = rp4[(size_t)(t0 + r) * 100 + q];
            }
        }
    };
    auto store_chunk = [&](int ck, const float4 (&rg)[5]) {
        const int slot = ck & 1;
        const int t0 = ck * kC;
        #pragma unroll
        for (int i = 0; i < 5; ++i) {
            const int task = pid + 192 * i;
            if (task < kC * 100) {
                const int r = task / 100, q = task - r * 100;
                float s4 = 0.f;
                if (t0 + r < Tb) {
                    const float4 x = rg[i];
                    const float e0 = __expf(x.x), e1 = __expf(x.y);
                    const float e2 = __expf(x.z), e3 = __expf(x.w);
                    s4 = (e0 + e1) + (e2 + e3);           // unmasked: denominator
                    const int l0 = 4 * q;
                    float4 w4;                            // masked: recursion
                    w4.x = (l0 + 0 < Lb) ? e0 : 0.f;
                    w4.y = (l0 + 1 < Lb) ? e1 : 0.f;
                    w4.z = (l0 + 2 < Lb) ? e2 : 0.f;
                    w4.w = (l0 + 3 < Lb) ? e3 : 0.f;
                    *(float4*)&wbuf[slot][r][4 * q] = w4;
                }
                psum[slot][task] = s4;
            }
        }
    };

    double Ld = 0.0;   // sum over t of log(se_t) — wave 1
    auto reduce_lse = [&](int ck) {
        const int ps = ck & 1;
        const int r = lane >> 3, k = lane & 7;   // 8 rows x 8 lanes
        float s = 0.f;
        #pragma unroll
        for (int m = 0; m < 13; ++m) {
            const int q = k + 8 * m;
            if (q < 100) s += psum[ps][r * 100 + q];
        }
        s += __shfl_xor(s, 1);
        s += __shfl_xor(s, 2);
        s += __shfl_xor(s, 4);
        float lv = (k == 0 && (ck * kC + r) < Tb) ? __logf(s + kEblank) : 0.f;
        lv += __shfl_xor(lv, 8);
        lv += __shfl_xor(lv, 16);
        lv += __shfl_xor(lv, 32);
        Ld += (double)lv;
    };

    // ---------------- consumer (wave 0) ----------------
    const int gi  = (lane < 50) ? lane : 50;     // weight group (50 = guards)
    float a[16];
    #pragma unroll
    for (int i = 0; i < 16; ++i) a[i] = 0.f;
    double Ct = 0.0;      // applied log-rescales
    float red = 1.0f;     // in-flight rescale reduction (neutral)

    // lane-1 shift, pure VALU: single DPP wave_shr:1 (0x138) across all 64
    // lanes; bound_ctrl=true -> lane 0 (invalid source) reads 0.
    auto shift1 = [&](float x) -> float {
        return __int_as_float(__builtin_amdgcn_update_dpp(
            0, __float_as_int(x), 0x138, 0xf, 0xf, true));
    };

    // one timestep, weights entirely in registers
    auto step_reg = [&](const float4 wlo, const float4 whi) {
        const float p1 = shift1(a[15]);
        float w[8];
        w[0] = wlo.x; w[1] = wlo.y; w[2] = wlo.z; w[3] = wlo.w;
        w[4] = whi.x; w[5] = whi.y; w[6] = whi.z; w[7] = whi.w;
        float n[16];
        {
            const float s = a[0] + p1;
            n[0] = kEblank * s;
            n[1] = w[0] * (a[1] + s);
        }
        #pragma unroll
        for (int j = 1; j < 8; ++j) {
            const float s = a[2 * j] + a[2 * j - 1];
            n[2 * j]     = kEblank * s;
            n[2 * j + 1] = w[j] * (a[2 * j + 1] + s);
        }
        #pragma unroll
        for (int i = 0; i < 16; ++i) a[i] = n[i];
    };
    // tail-only: per-step weight load (rare path)
    auto step_mem = [&](const float* __restrict__ wr_row) {
        const float4 wlo = *(const float4*)(wr_row);
        const float4 whi = *(const float4*)(wr_row + 4);
        step_reg(wlo, whi);
    };
    auto fold = [&]() {            // apply the just-completed reduction
        const float tot = red;
        const float c = 1.0f / tot;
        Ct += (double)__logf(tot);
        float ns = 0.f;
        #pragma unroll
        for (int i = 0; i < 16; ++i) { a[i] *= c; ns += a[i]; }
        red = ns;                  // new snapshot; butterfly runs next chunk
    };

#define PRELOAD(R)                                                      \
    const float4 WA##R = *(const float4*)(wr + (R) * kRow);             \
    const float4 WB##R = *(const float4*)(wr + (R) * kRow + 4);

    auto consumer_chunk = [&](int ck) {
        const float* wr = &wbuf[ck & 1][0][8 * gi];
        if (ck == 0) {
            PRELOAD(1) PRELOAD(2) PRELOAD(3) PRELOAD(4)
            PRELOAD(5) PRELOAD(6) PRELOAD(7)
            if (lane == 0) { a[0] = kEblank; a[1] = wbuf[0][0][0]; }
            step_reg(WA1, WB1);
            step_reg(WA2, WB2);
            step_reg(WA3, WB3);
            step_reg(WA4, WB4);
            step_reg(WA5, WB5);
            step_reg(WA6, WB6);
            step_reg(WA7, WB7);
            fold();                               // tot==1 no-op + snapshot
        } else if (ck < nck - 1) {                // full chunk, branch-free
            PRELOAD(0) PRELOAD(1) PRELOAD(2) PRELOAD(3)
            PRELOAD(4) PRELOAD(5) PRELOAD(6) PRELOAD(7)
            step_reg(WA0, WB0);  red += __shfl_xor(red, 1);
            step_reg(WA1, WB1);  red += __shfl_xor(red, 2);
            step_reg(WA2, WB2);  red += __shfl_xor(red, 4);
            step_reg(WA3, WB3);  red += __shfl_xor(red, 8);
            step_reg(WA4, WB4);  red += __shfl_xor(red, 16);
            step_reg(WA5, WB5);  red += __shfl_xor(red, 32);
            step_reg(WA6, WB6);
            step_reg(WA7, WB7);
            fold();
        } else {                                  // tail chunk (guarded)
            const int t0 = ck * kC;
            for (int r = 0; r < kC; ++r) {
                if (t0 + r >= Tb) break;
                step_mem(wr + r * kRow);
            }
        }
    };
#undef PRELOAD

    // preamble: stage chunk 0, prefetch chunk 1
    if (wv > 0) {
        load_chunk(0, rgE);
        store_chunk(0, rgE);
        load_chunk(1, rgO);
    }
    __syncthreads();

    for (int ck = 0; ck < nck; ck += 2) {
        // even chunk ck: consumer reads slot 0; producers fill slot 1
        if (wv == 0) {
            consumer_chunk(ck);
        } else {
            if (ck + 1 < nck) store_chunk(ck + 1, rgO);
            load_chunk(ck + 2, rgE);               // guarded by t < Tb inside
            if (wv == 1) reduce_lse(ck);
        }
        __syncthreads();
        // odd chunk ck+1: consumer reads slot 1; producers fill slot 0
        if (ck + 1 < nck) {
            if (wv == 0) {
                consumer_chunk(ck + 1);
            } else {
                if (ck + 2 < nck) store_chunk(ck + 2, rgE);
                load_chunk(ck + 3, rgO);
                if (wv == 1) reduce_lse(ck + 1);
            }
            __syncthreads();
        }
    }

    // ---------------- epilogue ----------------
    float* afin = (float*)wbuf;    // wbuf is dead now
    if (wv == 0 && lane <= 50) {
        #pragma unroll
        for (int i = 0; i < 16; ++i) afin[16 * lane + i] = a[i];
    }
    if (wv == 1 && lane == 0) sLd = Ld;
    __syncthreads();
    if (tid == 0) {
        const float tail = afin[Sb - 2] + afin[Sb - 1];
        const double la = (double)__logf(tail) + Ct - sLd;  // -inf if tail==0
        float loss = 0.f;
        if (la > -5e29) loss = (float)(-la / (double)Lb);
        loss_ws[b] = loss;
    }
}

__global__ void mean64_kernel(const float* __restrict__ loss_ws,
                              float* __restrict__ out) {
    float v = loss_ws[threadIdx.x];
    #pragma unroll
    for (int off = 32; off > 0; off >>= 1) v += __shfl_xor(v, off);
    if (threadIdx.x == 0) out[0] = v * (1.0f / 64.0f);
}

extern "C" void kernel_launch(void* const* d_in, const int* in_sizes, int n_in,
                              void* d_out, int out_size, void* d_ws, size_t ws_size,
                              hipStream_t stream) {
    const float* attn      = (const float*)d_in[0];
    const int*   text_lens = (const int*)d_in[1];
    const int*   mel_lens  = (const int*)d_in[2];
    float* loss_ws = (float*)d_ws;

    ctc_forward_kernel<<<kB, 256, 0, stream>>>(attn, text_lens, mel_lens, loss_ws);
    mean64_kernel<<<1, 64, 0, stream>>>(loss_ws, (float*)d_out);
}

// Round 6
// 526.445 us; speedup vs baseline: 1.6506x; 1.6506x over previous
//
#include <hip/hip_runtime.h>
#include <math.h>

// ForwardSumLoss (CTC forward), MI355X — fused single kernel + tiny mean.
// One block per batch. Wave 0: 801-state recursion in registers (16/lane),
// cross-lane hop = single DPP wave_shr:1 (pure VALU). Waves 1-3: producers.
// R6 CHANGE 1: all __syncthreads() replaced by a NO-VMCNT-DRAIN barrier
//   (s_waitcnt lgkmcnt(0); s_barrier). __syncthreads() emits
//   s_waitcnt vmcnt(0) before s_barrier, serially exposing the producers'
//   just-issued HBM prefetch (~900cy) at EVERY phase. Those loads target
//   registers consumed only next phase — the compiler's use-site counted
//   vmcnt waits already guarantee correctness; only ds_write visibility
//   (lgkmcnt) is needed at the barrier.
// R6 CHANGE 2: reduce_lse moved off wave 1 (parity-split waves 2/3) to
//   shorten the slowest producer's phase chain.
// [R5 lesson: phase cost is FLAT vs chunk size (2.75us/phase @kC=16 vs
//  2.66 @kC=8) -> time = nphases x fixed latency; the pole is the
//  producer's barrier-drain chain, not consumer VALU work.]
// [R4 lesson: ds_bpermute removal ~neutral; kept DPP anyway (free).]

namespace {
constexpr int kB = 64;
constexpr int kT = 2000;
constexpr int kL = 400;
constexpr int kC = 16;            // timesteps per chunk
constexpr int kRow = 408;         // floats per staged row (400 + 8 guard)
constexpr float kEblank = 0.36787944117144233f;   // exp(-1)
}

// Barrier WITHOUT vmcnt drain: LDS writes visible (lgkmcnt0), global loads
// stay in flight across the rendezvous. asm memory clobbers fence compiler
// code motion of memory ops in both directions.
__device__ __forceinline__ void barrier_nodrain() {
    asm volatile("s_waitcnt lgkmcnt(0)" ::: "memory");
    __builtin_amdgcn_s_barrier();
    asm volatile("" ::: "memory");
}

__global__ __launch_bounds__(256, 1) void ctc_forward_kernel(
        const float* __restrict__ attn, const int* __restrict__ text_lens,
        const int* __restrict__ mel_lens, float* __restrict__ loss_ws) {
    __shared__ __align__(16) float wbuf[2][kC][kRow];   // 52224 B
    __shared__ float psum[2][kC * 100];                 // 12800 B
    __shared__ double sLd2, sLd3;

    const int b    = blockIdx.x;
    const int tid  = threadIdx.x;
    const int lane = tid & 63;
    const int wv   = tid >> 6;
    const int Lb = text_lens[b];
    const int Tb = mel_lens[b];
    const int Sb = 2 * Lb + 1;
    const int nck = (Tb + kC - 1) / kC;

    const float4* __restrict__ rp4 = (const float4*)(attn + (size_t)b * kT * kL);

    // guard zeros: words [400,408) of every row, both slots (256 writes)
    {
        const int slot = tid >> 7, row = (tid >> 3) & 15, j = tid & 7;
        wbuf[slot][row][400 + j] = 0.f;
    }

    // ---------------- producers (waves 1-3) ----------------
    const int pid = tid - 64;          // 0..191
    float4 rgE[9], rgO[9];             // STATIC buffers — never runtime-indexed

    auto load_chunk = [&](int ck, float4 (&rg)[9]) {
        const int t0 = ck * kC;
        #pragma unroll
        for (int i = 0; i < 9; ++i) {
            const int task = pid + 192 * i;
            if (task < kC * 100) {
                const int r = task / 100, q = task - r * 100;
                if (t0 + r < Tb) rg[i] = rp4[(size_t)(t0 + r) * 100 + q];
            }
        }
    };
    auto store_chunk = [&](int ck, const float4 (&rg)[9]) {
        const int slot = ck & 1;
        const int t0 = ck * kC;
        #pragma unroll
        for (int i = 0; i < 9; ++i) {
            const int task = pid + 192 * i;
            if (task < kC * 100) {
                const int r = task / 100, q = task - r * 100;
                float s4 = 0.f;
                if (t0 + r < Tb) {
                    const float4 x = rg[i];
                    const float e0 = __expf(x.x), e1 = __expf(x.y);
                    const float e2 = __expf(x.z), e3 = __expf(x.w);
                    s4 = (e0 + e1) + (e2 + e3);           // unmasked: denominator
                    const int l0 = 4 * q;
                    float4 w4;                            // masked: recursion
                    w4.x = (l0 + 0 < Lb) ? e0 : 0.f;
                    w4.y = (l0 + 1 < Lb) ? e1 : 0.f;
                    w4.z = (l0 + 2 < Lb) ? e2 : 0.f;
                    w4.w = (l0 + 3 < Lb) ? e3 : 0.f;
                    *(float4*)&wbuf[slot][r][4 * q] = w4;
                }
                psum[slot][task] = s4;
            }
        }
    };

    double Ld = 0.0;   // partial sum over t of log(se_t) — waves 2 & 3
    auto reduce_lse = [&](int ck) {
        const int ps = ck & 1;
        const int r = lane >> 2, k = lane & 3;   // 16 rows x 4 lanes
        float s = 0.f;
        #pragma unroll
        for (int m = 0; m < 25; ++m) s += psum[ps][r * 100 + k + 4 * m];
        s += __shfl_xor(s, 1);
        s += __shfl_xor(s, 2);
        float lv = (k == 0 && (ck * kC + r) < Tb) ? __logf(s + kEblank) : 0.f;
        lv += __shfl_xor(lv, 4);
        lv += __shfl_xor(lv, 8);
        lv += __shfl_xor(lv, 16);
        lv += __shfl_xor(lv, 32);
        Ld += (double)lv;
    };

    // ---------------- consumer (wave 0) ----------------
    const int gi  = (lane < 50) ? lane : 50;     // weight group (50 = guards)
    float a[16];
    #pragma unroll
    for (int i = 0; i < 16; ++i) a[i] = 0.f;
    double Ct = 0.0;      // applied log-rescales
    float red = 1.0f;     // in-flight rescale reduction (neutral)

    // lane-1 shift, pure VALU: single DPP wave_shr:1 (0x138) across all 64
    // lanes; bound_ctrl=true -> lane 0 (invalid source) reads 0.
    auto shift1 = [&](float x) -> float {
        return __int_as_float(__builtin_amdgcn_update_dpp(
            0, __float_as_int(x), 0x138, 0xf, 0xf, true));
    };

    auto step = [&](const float* __restrict__ wr) {
        float w[8];
        *(float4*)&w[0] = *(const float4*)(wr);
        *(float4*)&w[4] = *(const float4*)(wr + 4);
        const float p1 = shift1(a[15]);
        float n[16];
        {
            const float s = a[0] + p1;
            n[0] = kEblank * s;
            n[1] = w[0] * (a[1] + s);
        }
        #pragma unroll
        for (int j = 1; j < 8; ++j) {
            const float s = a[2 * j] + a[2 * j - 1];
            n[2 * j]     = kEblank * s;
            n[2 * j + 1] = w[j] * (a[2 * j + 1] + s);
        }
        #pragma unroll
        for (int i = 0; i < 16; ++i) a[i] = n[i];
    };
    auto fold = [&]() {            // apply the just-completed reduction
        const float tot = red;
        const float c = 1.0f / tot;
        Ct += (double)__logf(tot);
        float ns = 0.f;
        #pragma unroll
        for (int i = 0; i < 16; ++i) { a[i] *= c; ns += a[i]; }
        red = ns;                  // new snapshot; butterfly runs next chunk
    };
    auto consumer_chunk = [&](int ck) {
        const float* wr = &wbuf[ck & 1][0][8 * gi];
        if (ck == 0) {
            if (lane == 0) { a[0] = kEblank; a[1] = wbuf[0][0][0]; }
            #pragma unroll
            for (int r = 1; r < kC; ++r) step(wr + r * kRow);
            fold();                               // tot==1 no-op + snapshot
        } else if (ck < nck - 1) {                // full chunk, branch-free
            step(wr);             red += __shfl_xor(red, 1);
            step(wr + kRow);      red += __shfl_xor(red, 2);
            step(wr + 2 * kRow);  red += __shfl_xor(red, 4);
            step(wr + 3 * kRow);  red += __shfl_xor(red, 8);
            step(wr + 4 * kRow);  red += __shfl_xor(red, 16);
            step(wr + 5 * kRow);  red += __shfl_xor(red, 32);
            #pragma unroll
            for (int r = 6; r < kC; ++r) step(wr + r * kRow);
            fold();
        } else {                                  // tail chunk (guarded)
            const int t0 = ck * kC;
            for (int r = 0; r < kC; ++r) {
                if (t0 + r >= Tb) break;
                step(wr + r * kRow);
            }
        }
    };

    // preamble: stage chunk 0, prefetch chunk 1
    if (wv > 0) {
        load_chunk(0, rgE);
        store_chunk(0, rgE);
        load_chunk(1, rgO);       // stays in flight across the barrier
    }
    barrier_nodrain();

    for (int ck = 0; ck < nck; ck += 2) {
        // even chunk ck: consumer reads slot 0; producers fill slot 1
        if (wv == 0) {
            consumer_chunk(ck);
        } else {
            if (ck + 1 < nck) store_chunk(ck + 1, rgO);
            load_chunk(ck + 2, rgE);               // guarded by t < Tb inside
            if (wv == 2) reduce_lse(ck);
        }
        barrier_nodrain();
        // odd chunk ck+1: consumer reads slot 1; producers fill slot 0
        if (ck + 1 < nck) {
            if (wv == 0) {
                consumer_chunk(ck + 1);
            } else {
                if (ck + 2 < nck) store_chunk(ck + 2, rgE);
                load_chunk(ck + 3, rgO);
                if (wv == 3) reduce_lse(ck + 1);
            }
            barrier_nodrain();
        }
    }

    // ---------------- epilogue ----------------
    float* afin = (float*)wbuf;    // wbuf is dead now
    if (wv == 0 && lane <= 50) {
        #pragma unroll
        for (int i = 0; i < 16; ++i) afin[16 * lane + i] = a[i];
    }
    if (wv == 2 && lane == 0) sLd2 = Ld;
    if (wv == 3 && lane == 0) sLd3 = Ld;
    barrier_nodrain();
    if (tid == 0) {
        const float tail = afin[Sb - 2] + afin[Sb - 1];
        const double la = (double)__logf(tail) + Ct - (sLd2 + sLd3);
        float loss = 0.f;
        if (la > -5e29) loss = (float)(-la / (double)Lb);
        loss_ws[b] = loss;
    }
}

__global__ void mean64_kernel(const float* __restrict__ loss_ws,
                              float* __restrict__ out) {
    float v = loss_ws[threadIdx.x];
    #pragma unroll
    for (int off = 32; off > 0; off >>= 1) v += __shfl_xor(v, off);
    if (threadIdx.x == 0) out[0] = v * (1.0f / 64.0f);
}

extern "C" void kernel_launch(void* const* d_in, const int* in_sizes, int n_in,
                              void* d_out, int out_size, void* d_ws, size_t ws_size,
                              hipStream_t stream) {
    const float* attn      = (const float*)d_in[0];
    const int*   text_lens = (const int*)d_in[1];
    const int*   mel_lens  = (const int*)d_in[2];
    float* loss_ws = (float*)d_ws;

    ctc_forward_kernel<<<kB, 256, 0, stream>>>(attn, text_lens, mel_lens, loss_ws);
    mean64_kernel<<<1, 64, 0, stream>>>(loss_ws, (float*)d_out);
}